// Round 7
// baseline (25.138 us; speedup 1.0000x reference)
//
#include <hip/hip_runtime.h>
#include <cfloat>

// Problem constants (from reference): B=8, C=2, H=256, W=256
#define BB 8
#define CC 2
#define HH 256
#define WW 256

typedef unsigned long long ull;

static constexpr float EDT_INF = 1e4f;          // matches reference INF
static constexpr int   NPIX    = BB * HH * WW;  // 524288

// ---------------------------------------------------------------------------
// 1D nearest-zero-bit distance^2 from a 256-bit mask, reproducing the
// reference f32 scan exactly: fwd d = m ? carry+1 : 0 (carry init 1e4),
// bwd symmetric, g = min(fwd,bwd), return g*g. pos = bit index.
__device__ __forceinline__ float g2_of(const ull* m, int pos, bool set) {
    if (!set) return 0.0f;
    float fwd = EDT_INF + (float)(pos + 1);   // run reaches low edge
    {
        int k = pos - 1;
        if (k >= 0) {
            int w = k >> 6;
            ull t = ~m[w] & (~0ULL >> (63 - (k & 63)));
            for (;;) {
                if (t) { int j = (w << 6) + 63 - __builtin_clzll(t); fwd = (float)(pos - j); break; }
                if (--w < 0) break;
                t = ~m[w];
            }
        }
    }
    float bwd = EDT_INF + (float)(256 - pos); // run reaches high edge
    {
        int k = pos + 1;
        if (k < 256) {
            int w = k >> 6;
            ull t = ~m[w] & (~0ULL << (k & 63));
            for (;;) {
                if (t) { int j = (w << 6) + __builtin_ctzll(t); bwd = (float)(j - pos); break; }
                if (++w >= 4) break;
                t = ~m[w];
            }
        }
    }
    float g = fminf(fwd, bwd);
    return g * g;
}

// ---------------------------------------------------------------------------
// K1: build ROW masks (coalesced: lanes across w) + per-block tmin partials.
// Grid: 256 blocks = b(8) x 8-row-group(32); 256 threads = 4 waves, wave wv
// covers w in [64*wv, 64*wv+64). Masks stored as mask[(b*256+i)*4 + wv].
// Three masks: pc (argmax preds), gt0 (tv>0), g255 (tv==255); the actual gt
// mask is fixed up in k_fused once tmin is known.
__global__ void k_masks(const float* __restrict__ preds,
                        const int*   __restrict__ target,
                        ull* __restrict__ mPC, ull* __restrict__ mGT0,
                        ull* __restrict__ mG255, int* __restrict__ tminPart) {
    const int blk = blockIdx.x;
    const int b  = blk >> 5;               // image
    const int ig = blk & 31;               // 8-row group
    const int wv = threadIdx.x >> 6;       // word index 0..3
    const int ln = threadIdx.x & 63;
    const int w  = (wv << 6) | ln;

    int tmin = 0x7fffffff;
#pragma unroll
    for (int r = 0; r < 8; ++r) {
        int i = ig * 8 + r;
        float a0 = preds[((size_t)b * CC + 0) * HH * WW + (size_t)i * WW + w];
        float a1 = preds[((size_t)b * CC + 1) * HH * WW + (size_t)i * WW + w];
        bool pc = (a1 > a0);               // argmax over C=2, ties -> class 0
        int tv = target[((size_t)b * HH + i) * WW + w];
        tmin = min(tmin, tv);
        ull bp = __ballot(pc);
        ull b0 = __ballot(tv > 0);
        ull b2 = __ballot(tv == 255);
        if (ln == 0) {
            size_t midx = ((size_t)b * HH + i) * 4 + wv;
            mPC[midx] = bp; mGT0[midx] = b0; mG255[midx] = b2;
        }
    }
    // wave shfl-min + 4-entry LDS merge (1 barrier)
    for (int off = 32; off > 0; off >>= 1) tmin = min(tmin, __shfl_down(tmin, off));
    __shared__ int swv[4];
    if (ln == 0) swv[wv] = tmin;
    __syncthreads();
    if (threadIdx.x == 0)
        tminPart[blk] = min(min(swv[0], swv[1]), min(swv[2], swv[3]));
}

// ---------------------------------------------------------------------------
// K2: fused per-COLUMN kernel (axis-swapped separable EDT: horizontal 1D
// distance from row masks, then vertical min_k h2[k] + (i-k)^2 — exact EDT).
// One block per (b,j); thread i = row. No global atomics.
__global__ void k_fused(const int* __restrict__ target,
                        const ull* __restrict__ mPC,
                        const ull* __restrict__ mGT0,
                        const ull* __restrict__ mG255,
                        const int* __restrict__ tminPart,
                        float* __restrict__ partials) {
    const int blk = blockIdx.x;            // b*256 + j
    const int b = blk >> 8, j = blk & 255;
    const int i = threadIdx.x;             // row
    const int wv = i >> 6, ln = i & 63;

    // tmin = min of the 256 k_masks partials: wave shfl + 4-entry merge
    __shared__ int stw[4];
    {
        int v = tminPart[i];
        for (int off = 32; off > 0; off >>= 1) v = min(v, __shfl_down(v, off));
        if (ln == 0) stw[wv] = v;
    }
    __syncthreads();
    const int tmin = min(min(stw[0], stw[1]), min(stw[2], stw[3]));
    const bool allpos = (tmin > 0);

    // row i's masks: 4 consecutive ULLs each -> coalesced dwordx4 loads
    ull wp[4], wg[4], np[4], ng[4];
    {
        const ull* pP = mPC   + ((size_t)b * HH + i) * 4;
        const ull* p0 = mGT0  + ((size_t)b * HH + i) * 4;
        const ull* p2 = mG255 + ((size_t)b * HH + i) * 4;
#pragma unroll
        for (int k = 0; k < 4; ++k) {
            wp[k] = pP[k];
            ull g = p0[k];
            if (!allpos) g &= ~p2[k];      // 255 -> tmin==0 -> not >0
            wg[k] = g;
            np[k] = ~wp[k]; ng[k] = ~wg[k];
        }
    }
    bool pc = (wp[j >> 6] >> (j & 63)) & 1ULL;
    bool gt = (wg[j >> 6] >> (j & 63)) & 1ULL;

    // stage the four horizontal distance^2 rows (value at (i,j) per polarity)
    __shared__ float s_pm[HH], s_pn[HH], s_gm[HH], s_gn[HH];
    s_pm[i] = g2_of(wp, j, pc);
    s_pn[i] = g2_of(np, j, !pc);
    s_gm[i] = g2_of(wg, j, gt);
    s_gn[i] = g2_of(ng, j, !gt);
    __syncthreads();

    // --- merged vertical searches (pc & gt), exact early exit for both ---
    const float* rv = pc ? s_pm : s_pn;
    const float* rw = gt ? s_gm : s_gn;
    float mn = rv[i];
    float mg = rw[i];
    for (int d = 1; d < HH; ++d) {
        float dd = (float)(d * d);
        if (__all((dd >= mn) & (dd >= mg))) break;
        int kl = i - d, kr = i + d;
        if (kl >= 0) { mn = fminf(mn, dd + rv[kl]); mg = fminf(mg, dd + rw[kl]); }
        if (kr < HH) { mn = fminf(mn, dd + rv[kr]); mg = fminf(mg, dd + rw[kr]); }
    }
    float pd = sqrtf(mn);
    float gd = sqrtf(mg);

    // --- final elementwise math (reference op order) ---
    int tv = target[((size_t)b * HH + i) * WW + j];   // uncoalesced, L2-fed
    if (tv == 255) tv = tmin;
    float gtv = (float)tv;
    float pcv = pc ? 1.0f : 0.0f;
    float err  = fabsf(gtv - pcv);
    float dist = sqrtf(pd * pd + gd * gd);
    float mult = sqrtf(err * dist + 1e-9f);

    // deterministic block sum: wave shfl-add + fixed-order 4-term merge
    __shared__ float sws[4];
    for (int off = 32; off > 0; off >>= 1) mult += __shfl_down(mult, off);
    if (ln == 0) sws[wv] = mult;
    __syncthreads();
    if (i == 0) partials[blk] = ((sws[0] + sws[1]) + sws[2]) + sws[3];
}

// ---------------------------------------------------------------------------
// K3: final deterministic reduction of B*W partials -> mean (fixed order)
__global__ void k_final(const float* __restrict__ partials, float* __restrict__ out) {
    __shared__ float s[256];
    float acc = 0.0f;
    for (int k = threadIdx.x; k < BB * WW; k += 256) acc += partials[k];
    s[threadIdx.x] = acc;
    __syncthreads();
    for (int st = 128; st > 0; st >>= 1) {
        if (threadIdx.x < st) s[threadIdx.x] += s[threadIdx.x + st];
        __syncthreads();
    }
    if (threadIdx.x == 0) out[0] = s[0] * (1.0f / (float)NPIX);  // /2^19: exact
}

// ---------------------------------------------------------------------------
extern "C" void kernel_launch(void* const* d_in, const int* in_sizes, int n_in,
                              void* d_out, int out_size, void* d_ws, size_t ws_size,
                              hipStream_t stream) {
    const float* preds  = (const float*)d_in[0];
    const int*   target = (const int*)d_in[1];
    float* out = (float*)d_out;

    // ws layout: 3 mask arrays (64 KB each), partials, tmin partials
    ull* mPC   = (ull*)d_ws;                         // 8*256*4 ULL
    ull* mGT0  = mPC  + (size_t)BB * HH * 4;
    ull* mG255 = mGT0 + (size_t)BB * HH * 4;
    float* partials = (float*)(mG255 + (size_t)BB * HH * 4);   // B*W floats
    int*   tminPart = (int*)(partials + BB * WW);              // 256 ints

    k_masks<<<256, 256, 0, stream>>>(preds, target, mPC, mGT0, mG255, tminPart);
    k_fused<<<BB * WW, HH, 0, stream>>>(target, mPC, mGT0, mG255, tminPart, partials);
    k_final<<<1, 256, 0, stream>>>(partials, out);
}